// Round 10
// baseline (216.109 us; speedup 1.0000x reference)
//
#include <hip/hip_runtime.h>
#include <hip/hip_cooperative_groups.h>
#include <math.h>

namespace cg = cooperative_groups;

#define QN 8
#define NDIMS 2
#define LATENT 64
#define OUTC 32     // Q + Q + Q*NDIMS
#define IT 16       // i-rows per tile in pair phase (pair_v1 config)

// ---------------------------------------------------------------------------
// feat body — VERBATIM logic of the round-5/6 shuffle feat (best measured).
// thread t -> (pt = t>>5, o = t&31). No early return hazards for shuffles:
// npts = 4096 -> whole waves are uniform in the pt<npts test.
// ---------------------------------------------------------------------------
__device__ __forceinline__ void feat_body(
    int t, const float* __restrict__ x, const float* __restrict__ y, int n,
    const float* __restrict__ W1, const float* __restrict__ b1,
    const float* __restrict__ W2, const float* __restrict__ b2,
    float* __restrict__ featX, float* __restrict__ featY, int lane)
{
    const int pt   = t >> 5;
    const int o    = t & 31;
    const int npts = 2 * n;
    if (pt >= npts) return;

    const float* p = (pt < n) ? (x + 2 * pt) : (y + 2 * (pt - n));
    float p0 = p[0], p1 = p[1];

    const float kScale = 1.0507009873554804934193349852946f;
    const float kAlpha = 1.6732632423543772848170429916717f;

    const float4* w2v = (const float4*)(W2 + o * LATENT);
    float z0 = b2[o], z1 = 0.f, z2 = 0.f, z3 = 0.f;
    #pragma unroll
    for (int c = 0; c < LATENT / 16; ++c) {
        float hb[16];
        #pragma unroll
        for (int r = 0; r < 16; ++r) {
            int k = 16 * c + r;
            float zz = fmaf(W1[2 * k], p0, fmaf(W1[2 * k + 1], p1, b1[k]));
            hb[r] = kScale * (zz > 0.f ? zz : kAlpha * (__expf(zz) - 1.f));
        }
        float4 w0 = w2v[4 * c + 0];
        float4 w1v = w2v[4 * c + 1];
        float4 w2q = w2v[4 * c + 2];
        float4 w3 = w2v[4 * c + 3];
        z0 = fmaf(w0.x,  hb[0],  fmaf(w0.y,  hb[1],  fmaf(w0.z,  hb[2],  fmaf(w0.w,  hb[3],  z0))));
        z1 = fmaf(w1v.x, hb[4],  fmaf(w1v.y, hb[5],  fmaf(w1v.z, hb[6],  fmaf(w1v.w, hb[7],  z1))));
        z2 = fmaf(w2q.x, hb[8],  fmaf(w2q.y, hb[9],  fmaf(w2q.z, hb[10], fmaf(w2q.w, hb[11], z2))));
        z3 = fmaf(w3.x,  hb[12], fmaf(w3.y,  hb[13], fmaf(w3.z,  hb[14], fmaf(w3.w,  hb[15], z3))));
    }
    float z = (z0 + z1) + (z2 + z3);
    float av = fmaxf(z, 0.f) + __logf(1.f + __expf(-fabsf(z)));

    const int base = lane & 32;               // half-wave owning this point
    const int q    = lane & 7;
    float w_ = __shfl(av, base + q, 64);
    float s_ = __shfl(av, base + 8 + q, 64);
    float f0 = __shfl(av, base + 16 + 2 * q, 64);
    float f1 = __shfl(av, base + 17 + 2 * q, 64);

    if ((lane & 31) < 8) {
        const float TWO_PI  = 6.283185307179586f;
        const float ROOT4_2 = 1.18920711500272107f;   // 2^(1/4)
        float phi = fmaf(f0, p0, f1 * p1);
        float rr  = phi - floorf(phi);
        float ang = TWO_PI * rr;
        float* fo = (pt < n) ? (featX + 32 * pt) : (featY + 32 * (pt - n));
        fo[q]          = w_ * sqrtf(s_) * ROOT4_2;
        fo[QN + q]     = s_ * s_;
        fo[2 * QN + q] = __cosf(ang);
        fo[3 * QN + q] = __sinf(ang);
    }
}

// ---------------------------------------------------------------------------
// pair body — VERBATIM logic of the round-6 pair_v1 (best measured).
// tile (bx, by): bx = j-block (256 j's), by = i-tile (IT=16 i's).
// Contains a __syncthreads(); must be entered by all threads of the block.
// ---------------------------------------------------------------------------
__device__ __forceinline__ void pair_body(
    int bx, int by, int tid,
    const float* __restrict__ x, const float* __restrict__ y, int n,
    const float* __restrict__ fA, const float* __restrict__ fB,
    float* __restrict__ out, float* faS, float* xaS)
{
    const int i0 = by * IT;

    if (tid < IT * 8) {                                 // 128 float4s of fA
        ((float4*)faS)[tid] = ((const float4*)(fA + (size_t)i0 * 32))[tid];
    } else if (tid < IT * 8 + IT / 2) {                 // 8 float4s of x
        ((float4*)xaS)[tid - IT * 8] = ((const float4*)(x + 2 * i0))[tid - IT * 8];
    }
    __syncthreads();

    const int j = bx * 256 + tid;
    if (j >= n) return;     // no barriers after this point

    const float4* fb4 = (const float4*)(fB + 32 * j);
    float4 fu0 = fb4[0], fu1 = fb4[1];
    float4 fs0 = fb4[2], fs1 = fb4[3];
    float4 fc0 = fb4[4], fc1 = fb4[5];
    float4 fn0 = fb4[6], fn1 = fb4[7];
    float uB[QN]  = {fu0.x,fu0.y,fu0.z,fu0.w, fu1.x,fu1.y,fu1.z,fu1.w};
    float ssB[QN] = {fs0.x,fs0.y,fs0.z,fs0.w, fs1.x,fs1.y,fs1.z,fs1.w};
    float cB[QN]  = {fc0.x,fc0.y,fc0.z,fc0.w, fc1.x,fc1.y,fc1.z,fc1.w};
    float snB[QN] = {fn0.x,fn0.y,fn0.z,fn0.w, fn1.x,fn1.y,fn1.z,fn1.w};

    float2 yv = *(const float2*)(y + 2 * j);
    const float LOG2E = 1.4426950408889634f;

    #pragma unroll 2
    for (int ii = 0; ii < IT; ++ii) {
        int i = i0 + ii;
        if (i >= n) break;

        const float4* fa4 = (const float4*)(faS + ii * 32);
        float4 au0 = fa4[0], au1 = fa4[1];
        float4 as0 = fa4[2], as1 = fa4[3];
        float4 ac0 = fa4[4], ac1 = fa4[5];
        float4 an0 = fa4[6], an1 = fa4[7];
        float uA[QN]  = {au0.x,au0.y,au0.z,au0.w, au1.x,au1.y,au1.z,au1.w};
        float ssA[QN] = {as0.x,as0.y,as0.z,as0.w, as1.x,as1.y,as1.z,as1.w};
        float cA[QN]  = {ac0.x,ac0.y,ac0.z,ac0.w, ac1.x,ac1.y,ac1.z,ac1.w};
        float snA[QN] = {an0.x,an0.y,an0.z,an0.w, an1.x,an1.y,an1.z,an1.w};

        float dx  = xaS[2 * ii]     - yv.x;
        float dy  = xaS[2 * ii + 1] - yv.y;
        float d2l = fmaf(dx, dx, dy * dy) * LOG2E;   // d2 * log2(e)

        float acc = 0.f;
        #pragma unroll
        for (int q = 0; q < QN; ++q) {
            float s2  = ssA[q] + ssB[q];
            float inv = __builtin_amdgcn_rcpf(s2);
            float e   = __builtin_amdgcn_exp2f(-d2l * inv);   // exp(-d2/s2)
            float g   = uA[q] * uB[q] * inv * e;
            float c   = fmaf(cA[q], cB[q], snA[q] * snB[q]);
            acc = fmaf(g, c, acc);
        }
        out[(long)i * n + j] = acc;
    }
}

// ---------------------------------------------------------------------------
// FUSED cooperative kernel: phase 1 = feat, grid-wide sync, phase 2 = pair.
// 1024 blocks x 256 threads; __launch_bounds__(256,4) guarantees 4 blocks/CU
// -> 1024 co-resident on 256 CUs, so the cooperative launch cannot fail on
// occupancy. Saves one graph dispatch + the inter-kernel drain.
// ---------------------------------------------------------------------------
__global__ __launch_bounds__(256, 4) void fused_kernel(
    const float* __restrict__ x, const float* __restrict__ y, int n,
    const float* __restrict__ W1, const float* __restrict__ b1,
    const float* __restrict__ W2, const float* __restrict__ b2,
    float* __restrict__ featX, float* __restrict__ featY,
    float* __restrict__ out)
{
    __shared__ __align__(16) float faS[IT * 32];       // 2 KB
    __shared__ __align__(16) float xaS[IT * 2];        // 128 B

    const int tid  = threadIdx.x;
    const int lane = tid & 63;

    // ---- phase 1: features (blocks >= 512 fall through) ----
    feat_body(blockIdx.x * 256 + tid, x, y, n, W1, b1, W2, b2,
              featX, featY, lane);

    // ---- make feature stores visible device-wide, then grid barrier ----
    __threadfence();
    cg::this_grid().sync();

    // ---- phase 2: pairwise tiles; 1024 blocks = 8 j-blocks x 128 i-tiles --
    pair_body(blockIdx.x & 7, blockIdx.x >> 3, tid,
              x, y, n, featX, featY, out, faS, xaS);
}

// ---------------------------------------------------------------------------
// Fallback two-kernel path (byte-identical math) if cooperative launch fails.
// ---------------------------------------------------------------------------
__global__ __launch_bounds__(256) void feat_kernel(
    const float* __restrict__ x, const float* __restrict__ y, int n,
    const float* __restrict__ W1, const float* __restrict__ b1,
    const float* __restrict__ W2, const float* __restrict__ b2,
    float* __restrict__ featX, float* __restrict__ featY)
{
    feat_body(blockIdx.x * 256 + threadIdx.x, x, y, n, W1, b1, W2, b2,
              featX, featY, threadIdx.x & 63);
}

__global__ __launch_bounds__(256) void pair_kernel(
    const float* __restrict__ x, const float* __restrict__ y, int n,
    const float* __restrict__ fA, const float* __restrict__ fB,
    float* __restrict__ out)
{
    __shared__ __align__(16) float faS[IT * 32];
    __shared__ __align__(16) float xaS[IT * 2];
    pair_body(blockIdx.x, blockIdx.y, threadIdx.x, x, y, n, fA, fB, out,
              faS, xaS);
}

extern "C" void kernel_launch(void* const* d_in, const int* in_sizes, int n_in,
                              void* d_out, int out_size, void* d_ws, size_t ws_size,
                              hipStream_t stream)
{
    const float* x  = (const float*)d_in[0];
    const float* y  = (const float*)d_in[1];
    const float* W1 = (const float*)d_in[2];
    const float* b1 = (const float*)d_in[3];
    const float* W2 = (const float*)d_in[4];
    const float* b2 = (const float*)d_in[5];
    float* out = (float*)d_out;

    int n = in_sizes[0] / NDIMS;     // 2048

    float* featX = (float*)d_ws;
    float* featY = featX + (size_t)n * 32;

    void* args[] = { (void*)&x, (void*)&y, (void*)&n, (void*)&W1, (void*)&b1,
                     (void*)&W2, (void*)&b2, (void*)&featX, (void*)&featY,
                     (void*)&out };
    hipError_t err = hipLaunchCooperativeKernel(
        (const void*)fused_kernel, dim3(1024), dim3(256), args, 0, stream);

    if (err != hipSuccess) {
        // fallback: proven two-kernel path (identical math)
        int npts = 2 * n;
        int featThreads = npts * OUTC;
        hipLaunchKernelGGL(feat_kernel, dim3((featThreads + 255) / 256),
                           dim3(256), 0, stream,
                           x, y, n, W1, b1, W2, b2, featX, featY);
        dim3 grid((n + 255) / 256, (n + IT - 1) / IT);
        hipLaunchKernelGGL(pair_kernel, grid, dim3(256), 0, stream,
                           x, y, n, featX, featY, out);
    }
}

// Round 11
// 27.106 us; speedup vs baseline: 7.9727x; 7.9727x over previous
//
#include <hip/hip_runtime.h>
#include <math.h>

#define QN 8
#define NDIMS 2
#define LATENT 64
#define OUTC 32     // Q + Q + Q*NDIMS
#define IT 8        // i-rows per block tile in pair kernel
#define JPT 2       // j's per thread in pair kernel

// ---------------------------------------------------------------------------
// Phase 1: feature MLP — BYTE-IDENTICAL to round 5/6 (best-total feat).
// One thread per (point, output-unit); 2048 waves; no LDS/barriers/spills.
// Store per point (32 floats):
//   [0:8) u=w*sqrt(s)*2^.25 | [8:16) s^2 | [16:24) cos 2pi*phi | [24:32) sin
// ---------------------------------------------------------------------------
__global__ __launch_bounds__(256) void feat_kernel(
    const float* __restrict__ x, const float* __restrict__ y, int n,
    const float* __restrict__ W1, const float* __restrict__ b1,
    const float* __restrict__ W2, const float* __restrict__ b2,
    float* __restrict__ featX, float* __restrict__ featY)
{
    const int t    = blockIdx.x * 256 + threadIdx.x;
    const int pt   = t >> 5;                 // point index (2 points per wave)
    const int o    = t & 31;                 // output unit for this lane
    const int npts = 2 * n;
    if (pt >= npts) return;

    const float* p = (pt < n) ? (x + 2 * pt) : (y + 2 * (pt - n));
    float p0 = p[0], p1 = p[1];

    const float kScale = 1.0507009873554804934193349852946f;
    const float kAlpha = 1.6732632423543772848170429916717f;

    const float4* w2v = (const float4*)(W2 + o * LATENT);
    float z0 = b2[o], z1 = 0.f, z2 = 0.f, z3 = 0.f;
    #pragma unroll
    for (int c = 0; c < LATENT / 16; ++c) {
        float hb[16];
        #pragma unroll
        for (int r = 0; r < 16; ++r) {
            int k = 16 * c + r;
            float zz = fmaf(W1[2 * k], p0, fmaf(W1[2 * k + 1], p1, b1[k]));
            hb[r] = kScale * (zz > 0.f ? zz : kAlpha * (__expf(zz) - 1.f));
        }
        float4 w0 = w2v[4 * c + 0];
        float4 w1v = w2v[4 * c + 1];
        float4 w2q = w2v[4 * c + 2];
        float4 w3 = w2v[4 * c + 3];
        z0 = fmaf(w0.x,  hb[0],  fmaf(w0.y,  hb[1],  fmaf(w0.z,  hb[2],  fmaf(w0.w,  hb[3],  z0))));
        z1 = fmaf(w1v.x, hb[4],  fmaf(w1v.y, hb[5],  fmaf(w1v.z, hb[6],  fmaf(w1v.w, hb[7],  z1))));
        z2 = fmaf(w2q.x, hb[8],  fmaf(w2q.y, hb[9],  fmaf(w2q.z, hb[10], fmaf(w2q.w, hb[11], z2))));
        z3 = fmaf(w3.x,  hb[12], fmaf(w3.y,  hb[13], fmaf(w3.z,  hb[14], fmaf(w3.w,  hb[15], z3))));
    }
    float z = (z0 + z1) + (z2 + z3);
    float av = fmaxf(z, 0.f) + __logf(1.f + __expf(-fabsf(z)));

    const int lane = threadIdx.x & 63;
    const int base = lane & 32;               // half-wave owning this point
    const int q    = lane & 7;
    float w_ = __shfl(av, base + q, 64);
    float s_ = __shfl(av, base + 8 + q, 64);
    float f0 = __shfl(av, base + 16 + 2 * q, 64);
    float f1 = __shfl(av, base + 17 + 2 * q, 64);

    if ((lane & 31) < 8) {
        const float TWO_PI  = 6.283185307179586f;
        const float ROOT4_2 = 1.18920711500272107f;   // 2^(1/4)
        float phi = fmaf(f0, p0, f1 * p1);
        float rr  = phi - floorf(phi);
        float ang = TWO_PI * rr;
        float* fo = (pt < n) ? (featX + 32 * pt) : (featY + 32 * (pt - n));
        fo[q]          = w_ * sqrtf(s_) * ROOT4_2;
        fo[QN + q]     = s_ * s_;
        fo[2 * QN + q] = __cosf(ang);
        fo[3 * QN + q] = __sinf(ang);
    }
}

// ---------------------------------------------------------------------------
// Phase 2: pair_v3 — JPT=2, IT=8.
// vs pair_v1: halves broadcast ds_read work per CU (8 reads/ii serve 2 j's)
// while KEEPING 16 waves/CU (1024 blocks; ~120 VGPR -> 4 waves/SIMD), which
// is what pair_v2 (JPT=4, ~128-reg B-state) lost.
// Model: LDS 16w x 64rd x 12cy = 12.3Kcy ~ 5.1us; VALU ~3.2us.
// out[i,j] = sum_q uA*uB/s2 * exp(-d2/s2) * (cA*cB + snA*snB),  s2=ssqA+ssqB
// ---------------------------------------------------------------------------
__global__ __launch_bounds__(256) void pair_kernel(
    const float* __restrict__ x, const float* __restrict__ y, int n,
    const float* __restrict__ fA, const float* __restrict__ fB,
    float* __restrict__ out)
{
    __shared__ __align__(16) float faS[IT * 32];       // 1 KB
    __shared__ __align__(16) float xaS[IT * 2];        // 64 B

    const int tid = threadIdx.x;
    const int i0  = blockIdx.y * IT;

    // ---- cooperative stage of the i-tile (coalesced float4) ----
    if (tid < IT * 8) {                                 // 64 float4s of fA
        ((float4*)faS)[tid] = ((const float4*)(fA + (size_t)i0 * 32))[tid];
    } else if (tid < IT * 8 + IT / 2) {                 // 4 float4s of x
        ((float4*)xaS)[tid - IT * 8] = ((const float4*)(x + 2 * i0))[tid - IT * 8];
    }
    __syncthreads();

    const int j0 = blockIdx.x * (256 * JPT) + tid * JPT;   // 2 contiguous j's
    if (j0 >= n) return;     // no barriers after this point

    // ---- B-side features for 2 j's into registers (static indices) --------
    float uB[JPT][QN], ssB[JPT][QN], cB[JPT][QN], snB[JPT][QN];
    float yj0[JPT], yj1[JPT];
    #pragma unroll
    for (int jj = 0; jj < JPT; ++jj) {
        const float4* fb4 = (const float4*)(fB + 32 * (j0 + jj));
        float4 a0 = fb4[0], a1 = fb4[1], a2 = fb4[2], a3 = fb4[3];
        float4 a4 = fb4[4], a5 = fb4[5], a6 = fb4[6], a7 = fb4[7];
        uB[jj][0]=a0.x; uB[jj][1]=a0.y; uB[jj][2]=a0.z; uB[jj][3]=a0.w;
        uB[jj][4]=a1.x; uB[jj][5]=a1.y; uB[jj][6]=a1.z; uB[jj][7]=a1.w;
        ssB[jj][0]=a2.x; ssB[jj][1]=a2.y; ssB[jj][2]=a2.z; ssB[jj][3]=a2.w;
        ssB[jj][4]=a3.x; ssB[jj][5]=a3.y; ssB[jj][6]=a3.z; ssB[jj][7]=a3.w;
        cB[jj][0]=a4.x; cB[jj][1]=a4.y; cB[jj][2]=a4.z; cB[jj][3]=a4.w;
        cB[jj][4]=a5.x; cB[jj][5]=a5.y; cB[jj][6]=a5.z; cB[jj][7]=a5.w;
        snB[jj][0]=a6.x; snB[jj][1]=a6.y; snB[jj][2]=a6.z; snB[jj][3]=a6.w;
        snB[jj][4]=a7.x; snB[jj][5]=a7.y; snB[jj][6]=a7.z; snB[jj][7]=a7.w;
        float2 yv = *(const float2*)(y + 2 * (j0 + jj));
        yj0[jj] = yv.x; yj1[jj] = yv.y;
    }

    const float NLOG2E = -1.4426950408889634f;

    #pragma unroll 2
    for (int ii = 0; ii < IT; ++ii) {
        int i = i0 + ii;
        if (i >= n) break;

        // broadcast ds_read_b128 of this i's features (all lanes same addr)
        const float4* fa4 = (const float4*)(faS + ii * 32);
        float4 b0 = fa4[0], b1v = fa4[1], b2v = fa4[2], b3 = fa4[3];
        float4 b4 = fa4[4], b5 = fa4[5], b6 = fa4[6], b7 = fa4[7];
        float uA[QN]  = {b0.x,b0.y,b0.z,b0.w, b1v.x,b1v.y,b1v.z,b1v.w};
        float ssA[QN] = {b2v.x,b2v.y,b2v.z,b2v.w, b3.x,b3.y,b3.z,b3.w};
        float cA[QN]  = {b4.x,b4.y,b4.z,b4.w, b5.x,b5.y,b5.z,b5.w};
        float snA[QN] = {b6.x,b6.y,b6.z,b6.w, b7.x,b7.y,b7.z,b7.w};
        float xi0 = xaS[2 * ii], xi1 = xaS[2 * ii + 1];

        float d2ln[JPT];
        #pragma unroll
        for (int jj = 0; jj < JPT; ++jj) {
            float dx = xi0 - yj0[jj];
            float dy = xi1 - yj1[jj];
            d2ln[jj] = fmaf(dx, dx, dy * dy) * NLOG2E;   // -d2*log2(e)
        }

        float2 accv;
        float* accp = &accv.x;
        #pragma unroll
        for (int jj = 0; jj < JPT; ++jj) {
            float acc = 0.f;
            #pragma unroll
            for (int q = 0; q < QN; ++q) {
                float s2  = ssA[q] + ssB[jj][q];
                float inv = __builtin_amdgcn_rcpf(s2);
                float e   = __builtin_amdgcn_exp2f(d2ln[jj] * inv);
                float t   = uA[q] * uB[jj][q];
                float c   = fmaf(cA[q], cB[jj][q], snA[q] * snB[jj][q]);
                acc = fmaf(t * inv * e, c, acc);
            }
            accp[jj] = acc;
        }
        *(float2*)(out + (long)i * n + j0) = accv;
    }
}

extern "C" void kernel_launch(void* const* d_in, const int* in_sizes, int n_in,
                              void* d_out, int out_size, void* d_ws, size_t ws_size,
                              hipStream_t stream)
{
    const float* x  = (const float*)d_in[0];
    const float* y  = (const float*)d_in[1];
    const float* W1 = (const float*)d_in[2];
    const float* b1 = (const float*)d_in[3];
    const float* W2 = (const float*)d_in[4];
    const float* b2 = (const float*)d_in[5];
    float* out = (float*)d_out;

    int n = in_sizes[0] / NDIMS;     // 2048

    float* featX = (float*)d_ws;
    float* featY = featX + (size_t)n * 32;

    int npts = 2 * n;
    int featThreads = npts * OUTC;                    // one thread per (pt, o)
    hipLaunchKernelGGL(feat_kernel, dim3((featThreads + 255) / 256), dim3(256), 0, stream,
                       x, y, n, W1, b1, W2, b2, featX, featY);

    dim3 grid((n + 256 * JPT - 1) / (256 * JPT), (n + IT - 1) / IT);
    hipLaunchKernelGGL(pair_kernel, grid, dim3(256), 0, stream,
                       x, y, n, featX, featY, out);
}